// Round 15
// baseline (323.578 us; speedup 1.0000x reference)
//
#include <hip/hip_runtime.h>
#include <math.h>

#define NB 8
#define NCH 30
#define LL 16384
#define N1 6000
#define N2 4914
#define NCLS 5
#define KLIM 8192
#define ATT_K 13

typedef float f32x4 __attribute__((ext_vector_type(4)));

__device__ __forceinline__ unsigned fkey(float f) {
  unsigned u = __float_as_uint(f);
  unsigned m = (unsigned)(((int)u) >> 31) | 0x80000000u;
  return u ^ m;  // order-preserving float->uint
}
__device__ __forceinline__ float sigmoidf(float x) { return 1.f / (1.f + expf(-x)); }

// ---- K1: per-(b,c) mean pool over HxH = 16384 ----
__global__ void k_pool(const float* __restrict__ adj, float* __restrict__ pooled) {
  int bc = blockIdx.x;                       // 0..239
  const float* p = adj + (size_t)bc * LL;
  int tid = threadIdx.x;
  float s = 0.f;
  #pragma unroll
  for (int it = 0; it < LL / (256 * 4); ++it) {
    float4 v = *(const float4*)(p + it * 1024 + tid * 4);
    s += v.x + v.y + v.z + v.w;
  }
  #pragma unroll
  for (int m = 1; m < 64; m <<= 1) s += __shfl_xor(s, m);
  __shared__ float red[4];
  if ((tid & 63) == 0) red[tid >> 6] = s;
  __syncthreads();
  if (tid == 0) pooled[bc] = (red[0] + red[1] + red[2] + red[3]) * (1.f / (float)LL);
}

// ---- K2 (fused eca+wsum) ----
__global__ void k_wsum(const float* __restrict__ adj, const float* __restrict__ pooled,
                       const float* __restrict__ ew, float* __restrict__ y,
                       float* __restrict__ pmm, float* __restrict__ band_out) {
  int blk = blockIdx.x;                       // b*16 + tile
  int b = blk >> 4, tile = blk & 15;
  int tid = threadIdx.x;
  __shared__ float sc[NCH];
  if (tid < NCH) {
    int c = tid;
    const float* p = pooled + b * NCH;
    float s = ew[1] * p[c];
    if (c > 0)       s += ew[0] * p[c - 1];
    if (c < NCH - 1) s += ew[2] * p[c + 1];
    float scv = sigmoidf(s);
    sc[c] = scv;
    if (tile == 0) band_out[b * NCH + c] = scv;
  }
  __syncthreads();
  int j = tile * 1024 + tid * 4;
  const float* base = adj + (size_t)b * NCH * LL + j;
  float4 acc = {0.f, 0.f, 0.f, 0.f};
  #pragma unroll
  for (int c = 0; c < NCH; ++c) {
    float4 v = *(const float4*)(base + (size_t)c * LL);
    float s = sc[c];
    acc.x += v.x * s; acc.y += v.y * s; acc.z += v.z * s; acc.w += v.w * s;
  }
  *(float4*)(y + b * LL + j) = acc;
  float mn = fminf(fminf(acc.x, acc.y), fminf(acc.z, acc.w));
  float mx = fmaxf(fmaxf(acc.x, acc.y), fmaxf(acc.z, acc.w));
  #pragma unroll
  for (int m = 1; m < 64; m <<= 1) {
    mn = fminf(mn, __shfl_xor(mn, m));
    mx = fmaxf(mx, __shfl_xor(mx, m));
  }
  __shared__ float wmn[4], wmx[4];
  if ((tid & 63) == 0) { wmn[tid >> 6] = mn; wmx[tid >> 6] = mx; }
  __syncthreads();
  if (tid == 0) {
    mn = fminf(fminf(wmn[0], wmn[1]), fminf(wmn[2], wmn[3]));
    mx = fmaxf(fmaxf(wmx[0], wmx[1]), fmaxf(wmx[2], wmx[3]));
    pmm[blk * 2 + 0] = mn; pmm[blk * 2 + 1] = mx;
  }
}

// ---- K3 (fused): normalize -> conv13 -> exact top-8192 select -> scatter sparse ----
__global__ __launch_bounds__(1024) void k_selfuse(const float* __restrict__ y,
                                                  const float* __restrict__ pmm,
                                                  const float* __restrict__ w,
                                                  float* __restrict__ sp) {
  int b = blockIdx.x;
  int tid = threadIdx.x;
  int wave = tid >> 6, lane = tid & 63;
  extern __shared__ float vsh[];            // 16896 floats, idx(j) = j + (j>>5)
  __shared__ float wl[ATT_K];
  __shared__ int redw[16][3];
  __shared__ int ctot[3];
  __shared__ int wtot[16];
  if (tid < ATT_K) wl[tid] = w[tid];

  float mn = pmm[b * 32], mx = pmm[b * 32 + 1];
  #pragma unroll
  for (int t = 1; t < 16; ++t) {
    mn = fminf(mn, pmm[b * 32 + t * 2]);
    mx = fmaxf(mx, pmm[b * 32 + t * 2 + 1]);
  }
  float inv = 1.f / (mx - mn);

  const float* yb = y + b * LL;
  #pragma unroll
  for (int c = 0; c < 4; ++c) {
    int i = c * 4096 + tid * 4;
    float4 t4 = *(const float4*)(yb + i);
    int p0 = i + (i >> 5);
    vsh[p0 + 0] = (t4.x - mn) * inv;
    vsh[p0 + 1] = (t4.y - mn) * inv;
    vsh[p0 + 2] = (t4.z - mn) * inv;
    vsh[p0 + 3] = (t4.w - mn) * inv;
  }
  __syncthreads();

  int e = tid * 16;
  unsigned kk[16];
  {
    float v28[28];
    #pragma unroll
    for (int i = 0; i < 28; ++i) {
      int j = e - 6 + i;
      v28[i] = (j >= 0 && j < LL) ? vsh[j + (j >> 5)] : 0.f;
    }
    #pragma unroll
    for (int i = 0; i < 16; ++i) {
      float acc = 0.f;
      #pragma unroll
      for (int k = 0; k < ATT_K; ++k) acc += v28[i + k] * wl[k];
      kk[i] = fkey(acc);
    }
  }

  unsigned p = 0; int need = KLIM;
  for (int pass = 0; pass < 16; ++pass) {
    int sh = 30 - pass * 2;
    unsigned himask = (pass == 0) ? 0u : (0xFFFFFFFFu << (sh + 2));
    int c3 = 0, c2 = 0, c1 = 0;
    #pragma unroll
    for (int i = 0; i < 16; ++i) {
      unsigned k2 = kk[i];
      if ((k2 & himask) == p) {
        unsigned bk = (k2 >> sh) & 3u;
        c3 += (bk == 3); c2 += (bk == 2); c1 += (bk == 1);
      }
    }
    #pragma unroll
    for (int m = 1; m < 64; m <<= 1) {
      c3 += __shfl_xor(c3, m); c2 += __shfl_xor(c2, m); c1 += __shfl_xor(c1, m);
    }
    if (lane == 0) { redw[wave][0] = c3; redw[wave][1] = c2; redw[wave][2] = c1; }
    __syncthreads();
    if (wave == 0) {
      int a0 = 0, a1 = 0, a2 = 0;
      if (lane < 16) { a0 = redw[lane][0]; a1 = redw[lane][1]; a2 = redw[lane][2]; }
      #pragma unroll
      for (int m = 1; m < 16; m <<= 1) {
        a0 += __shfl_xor(a0, m); a1 += __shfl_xor(a1, m); a2 += __shfl_xor(a2, m);
      }
      if (lane == 0) { ctot[0] = a0; ctot[1] = a1; ctot[2] = a2; }
    }
    __syncthreads();
    int C3 = ctot[0], C2 = ctot[1], C1 = ctot[2];
    if (C3 >= need)                { p |= 3u << sh; }
    else if (C3 + C2 >= need)      { p |= 2u << sh; need -= C3; }
    else if (C3 + C2 + C1 >= need) { p |= 1u << sh; need -= C3 + C2; }
    else                           { need -= C3 + C2 + C1; }
  }

  int cnt = 0;
  #pragma unroll
  for (int i = 0; i < 16; ++i) cnt += (kk[i] == p);
  int pre = cnt;
  #pragma unroll
  for (int m = 1; m < 64; m <<= 1) {
    int t = __shfl_up(pre, m);
    if (lane >= m) pre += t;
  }
  if (lane == 63) wtot[wave] = pre;
  __syncthreads();
  int base = 0;
  for (int t = 0; t < 16; ++t) if (t < wave) base += wtot[t];
  int rank = base + pre - cnt;

  float v28[28];
  #pragma unroll
  for (int i = 0; i < 28; ++i) {
    int j = e - 6 + i;
    v28[i] = (j >= 0 && j < LL) ? vsh[j + (j >> 5)] : 0.f;
  }
  float outv[16];
  #pragma unroll
  for (int i = 0; i < 16; ++i) {
    float acc = 0.f;
    #pragma unroll
    for (int k = 0; k < ATT_K; ++k) acc += v28[i + k] * wl[k];
    bool sel;
    if (kk[i] > p) sel = true;
    else if (kk[i] == p) { sel = (rank < need); rank++; }
    else sel = false;
    outv[i] = sel ? v28[i + 6] * (sigmoidf(acc) + 1.f) : 0.f;
  }
  float* spb = sp + b * LL + e;
  #pragma unroll
  for (int q = 0; q < 4; ++q)
    *(f32x4*)(spb + q * 4) = *(f32x4*)(outv + q * 4);
}

// ---- K4: split-K GEMM1 partials (R8 body, unchanged) ----
__global__ __launch_bounds__(1024, 4) void k_gemm1(const float* __restrict__ W1,
                                                   const float* __restrict__ sp,
                                                   float* __restrict__ p1) {
  __shared__ float sps[8][2048];            // 64 KB
  int bid = blockIdx.x;
  int s = bid & 7, g = bid >> 3;            // split, row-group
  int tid = threadIdx.x, wave = tid >> 6, lane = tid & 63;
  #pragma unroll
  for (int i = 0; i < 4; ++i) {
    int idx = i * 1024 + tid;               // f32x4 index 0..4095
    int bb = idx >> 9, off = (idx & 511) * 4;
    *(f32x4*)&sps[bb][off] = *(const f32x4*)(sp + (size_t)bb * LL + s * 2048 + off);
  }
  __syncthreads();
  int r0 = g * 94;
  int nr = N1 - r0; if (nr > 94) nr = 94;   // always even (94 or 78)
  int npair = nr >> 1;
  for (int p = wave; p < npair; p += 16) {
    int rA = r0 + p * 2;
    const float* wpA = W1 + (size_t)rA * LL + s * 2048;
    const float* wpB = wpA + LL;
    float acc0[8], acc1[8];
    #pragma unroll
    for (int bb = 0; bb < 8; ++bb) { acc0[bb] = 0.f; acc1[bb] = 0.f; }
    #pragma unroll 2
    for (int it = 0; it < 8; ++it) {
      int k0 = it * 256 + lane * 4;
      f32x4 wA = __builtin_nontemporal_load((const f32x4*)(wpA + k0));
      f32x4 wB = __builtin_nontemporal_load((const f32x4*)(wpB + k0));
      #pragma unroll
      for (int bb = 0; bb < 8; ++bb) {
        f32x4 s4 = *(const f32x4*)&sps[bb][k0];
        acc0[bb] += wA.x * s4.x + wA.y * s4.y + wA.z * s4.z + wA.w * s4.w;
        acc1[bb] += wB.x * s4.x + wB.y * s4.y + wB.z * s4.z + wB.w * s4.w;
      }
    }
    #pragma unroll
    for (int bb = 0; bb < 8; ++bb) {
      float a0 = acc0[bb], a1 = acc1[bb];
      #pragma unroll
      for (int m = 1; m < 64; m <<= 1) {
        a0 += __shfl_xor(a0, m);
        a1 += __shfl_xor(a1, m);
      }
      if (lane == 0) {
        p1[(size_t)(s * 8 + bb) * N1 + rA]     = a0;
        p1[(size_t)(s * 8 + bb) * N1 + rA + 1] = a1;
      }
    }
  }
}

// ---- K5: split-K GEMM2 partials; 6 splits x 86 groups = 516 blocks (all CUs).
// ks = s*1024, klen = 1024 (880 for s==5, zero-padded + guarded loads).
__global__ __launch_bounds__(1024, 4) void k_gemm2(const float* __restrict__ W2,
                                                   const float* __restrict__ p1,
                                                   const float* __restrict__ b1,
                                                   float* __restrict__ p2) {
  __shared__ float hs[8][1024];             // 32 KB
  int bid = blockIdx.x;
  int s = bid / 86, g = bid % 86;
  int ks = s * 1024;
  int klen = (s == 5) ? (N1 - 5120) : 1024; // 880 for last split
  int tid = threadIdx.x, wave = tid >> 6, lane = tid & 63;
  #pragma unroll
  for (int i = 0; i < 2; ++i) {
    int idx = i * 1024 + tid;               // f32x4 slot 0..2047
    int bb = idx >> 8, off = (idx & 255) * 4;
    f32x4 v = {0.f, 0.f, 0.f, 0.f};
    if (off < klen) {
      int j = ks + off;
      #pragma unroll
      for (int q = 0; q < 8; ++q)
        v += *(const f32x4*)(p1 + (size_t)(q * 8 + bb) * N1 + j);
      v += *(const f32x4*)(b1 + j);
    }
    *(f32x4*)&hs[bb][off] = v;
  }
  __syncthreads();
  int r0 = g * 58;
  int nr = N2 - r0; if (nr > 58) nr = 58; if (nr < 0) nr = 0;  // even (58/42/0)
  int npair = nr >> 1;
  f32x4 z = {0.f, 0.f, 0.f, 0.f};
  for (int p = wave; p < npair; p += 16) {
    int rA = r0 + p * 2;
    const float* wpA = W2 + (size_t)rA * N1 + ks;
    const float* wpB = wpA + N1;
    float acc0[8], acc1[8];
    #pragma unroll
    for (int bb = 0; bb < 8; ++bb) { acc0[bb] = 0.f; acc1[bb] = 0.f; }
    #pragma unroll
    for (int it = 0; it < 4; ++it) {
      int k0 = it * 256 + lane * 4;
      bool inb = k0 < klen;
      f32x4 wA = inb ? __builtin_nontemporal_load((const f32x4*)(wpA + k0)) : z;
      f32x4 wB = inb ? __builtin_nontemporal_load((const f32x4*)(wpB + k0)) : z;
      #pragma unroll
      for (int bb = 0; bb < 8; ++bb) {
        f32x4 s4 = *(const f32x4*)&hs[bb][k0];
        acc0[bb] += wA.x * s4.x + wA.y * s4.y + wA.z * s4.z + wA.w * s4.w;
        acc1[bb] += wB.x * s4.x + wB.y * s4.y + wB.z * s4.z + wB.w * s4.w;
      }
    }
    #pragma unroll
    for (int bb = 0; bb < 8; ++bb) {
      float a0 = acc0[bb], a1 = acc1[bb];
      #pragma unroll
      for (int m = 1; m < 64; m <<= 1) {
        a0 += __shfl_xor(a0, m);
        a1 += __shfl_xor(a1, m);
      }
      if (lane == 0) {
        p2[(size_t)(s * 8 + bb) * N2 + rA]     = a0;
        p2[(size_t)(s * 8 + bb) * N2 + rA + 1] = a1;
      }
    }
  }
}

// ---- K6: t[b,m] = sum_n h2[b,n]*Wc1[m,n], h2 reconstructed from 6 partials + b2 ----
__global__ void k_cls1(const float* __restrict__ p2, const float* __restrict__ b2,
                       const float* __restrict__ Wc1, float* __restrict__ t) {
  int bid = blockIdx.x; int b = bid >> 5, m = bid & 31;
  int tid = threadIdx.x;
  const float* wm = Wc1 + m * N2;
  float s = 0.f;
  for (int j = tid; j < N2; j += 256) {
    float hv = p2[(size_t)(0 * 8 + b) * N2 + j]
             + p2[(size_t)(1 * 8 + b) * N2 + j]
             + p2[(size_t)(2 * 8 + b) * N2 + j]
             + p2[(size_t)(3 * 8 + b) * N2 + j]
             + p2[(size_t)(4 * 8 + b) * N2 + j]
             + p2[(size_t)(5 * 8 + b) * N2 + j] + b2[j];
    s += hv * wm[j];
  }
  #pragma unroll
  for (int mm = 1; mm < 64; mm <<= 1) s += __shfl_xor(s, mm);
  __shared__ float red[4];
  if ((tid & 63) == 0) red[tid >> 6] = s;
  __syncthreads();
  if (tid == 0) t[b * 32 + m] = red[0] + red[1] + red[2] + red[3];
}

// ---- K7: logits = t @ Wc2^T ; log_softmax ----
__global__ void k_final(const float* __restrict__ t, const float* __restrict__ Wc2,
                        float* __restrict__ out) {
  int b = threadIdx.x;
  if (b < NB) {
    float lg[NCLS];
    #pragma unroll
    for (int k = 0; k < NCLS; ++k) {
      float s = 0.f;
      #pragma unroll
      for (int m = 0; m < 32; ++m) s += t[b * 32 + m] * Wc2[k * 32 + m];
      lg[k] = s;
    }
    float mx = lg[0];
    #pragma unroll
    for (int k = 1; k < NCLS; ++k) mx = fmaxf(mx, lg[k]);
    float se = 0.f;
    #pragma unroll
    for (int k = 0; k < NCLS; ++k) se += expf(lg[k] - mx);
    float lse = logf(se);
    #pragma unroll
    for (int k = 0; k < NCLS; ++k) out[b * NCLS + k] = lg[k] - mx - lse;
  }
}

extern "C" void kernel_launch(void* const* d_in, const int* in_sizes, int n_in,
                              void* d_out, int out_size, void* d_ws, size_t ws_size,
                              hipStream_t stream) {
  const float* adj   = (const float*)d_in[0];
  const float* eca_w = (const float*)d_in[1];
  const float* att_w = (const float*)d_in[2];
  const float* W1    = (const float*)d_in[3];
  const float* b1    = (const float*)d_in[4];
  const float* W2    = (const float*)d_in[5];
  const float* b2    = (const float*)d_in[6];
  const float* Wc1   = (const float*)d_in[7];
  const float* Wc2   = (const float*)d_in[8];
  float* out = (float*)d_out;
  float* ws  = (float*)d_ws;

  float* pooled = ws;              // 240
  float* pmm    = ws + 512;        // 256
  float* tbuf   = ws + 768;        // 256
  float* y      = ws + 1024;       // 131072
  float* sp     = y  + NB * LL;    // 131072
  float* p1     = sp + NB * LL;    // 8*8*6000 = 384000
  float* p2     = p1 + 384000;     // 6*8*4914 = 235872

  k_pool   <<<NB * NCH, 256, 0, stream>>>(adj, pooled);
  k_wsum   <<<NB * 16, 256, 0, stream>>>(adj, pooled, eca_w, y, pmm, out + NB * NCLS);
  k_selfuse<<<NB, 1024, 16896 * sizeof(float), stream>>>(y, pmm, att_w, sp);
  k_gemm1  <<<8 * 64, 1024, 0, stream>>>(W1, sp, p1);
  k_gemm2  <<<6 * 86, 1024, 0, stream>>>(W2, p1, b1, p2);
  k_cls1   <<<NB * 32, 256, 0, stream>>>(p2, b2, Wc1, tbuf);
  k_final  <<<1, 64, 0, stream>>>(tbuf, Wc2, out);
}

// Round 16
// 173.760 us; speedup vs baseline: 1.8622x; 1.8622x over previous
//
#include <hip/hip_runtime.h>
#include <math.h>

#define NB 8
#define NCH 30
#define LL 16384
#define N1 6000
#define N2 4914
#define NCLS 5
#define KLIM 8192
#define ATT_K 13

typedef float f32x4 __attribute__((ext_vector_type(4)));

__device__ __forceinline__ unsigned fkey(float f) {
  unsigned u = __float_as_uint(f);
  unsigned m = (unsigned)(((int)u) >> 31) | 0x80000000u;
  return u ^ m;  // order-preserving float->uint
}
__device__ __forceinline__ float sigmoidf(float x) { return 1.f / (1.f + expf(-x)); }

// ---- K1: per-(b,c) mean pool over HxH = 16384 ----
__global__ void k_pool(const float* __restrict__ adj, float* __restrict__ pooled) {
  int bc = blockIdx.x;                       // 0..239
  const float* p = adj + (size_t)bc * LL;
  int tid = threadIdx.x;
  float s = 0.f;
  #pragma unroll
  for (int it = 0; it < LL / (256 * 4); ++it) {
    float4 v = *(const float4*)(p + it * 1024 + tid * 4);
    s += v.x + v.y + v.z + v.w;
  }
  #pragma unroll
  for (int m = 1; m < 64; m <<= 1) s += __shfl_xor(s, m);
  __shared__ float red[4];
  if ((tid & 63) == 0) red[tid >> 6] = s;
  __syncthreads();
  if (tid == 0) pooled[bc] = (red[0] + red[1] + red[2] + red[3]) * (1.f / (float)LL);
}

// ---- K2 (fused eca+wsum) ----
__global__ void k_wsum(const float* __restrict__ adj, const float* __restrict__ pooled,
                       const float* __restrict__ ew, float* __restrict__ y,
                       float* __restrict__ pmm, float* __restrict__ band_out) {
  int blk = blockIdx.x;                       // b*16 + tile
  int b = blk >> 4, tile = blk & 15;
  int tid = threadIdx.x;
  __shared__ float sc[NCH];
  if (tid < NCH) {
    int c = tid;
    const float* p = pooled + b * NCH;
    float s = ew[1] * p[c];
    if (c > 0)       s += ew[0] * p[c - 1];
    if (c < NCH - 1) s += ew[2] * p[c + 1];
    float scv = sigmoidf(s);
    sc[c] = scv;
    if (tile == 0) band_out[b * NCH + c] = scv;
  }
  __syncthreads();
  int j = tile * 1024 + tid * 4;
  const float* base = adj + (size_t)b * NCH * LL + j;
  float4 acc = {0.f, 0.f, 0.f, 0.f};
  #pragma unroll
  for (int c = 0; c < NCH; ++c) {
    float4 v = *(const float4*)(base + (size_t)c * LL);
    float s = sc[c];
    acc.x += v.x * s; acc.y += v.y * s; acc.z += v.z * s; acc.w += v.w * s;
  }
  *(float4*)(y + b * LL + j) = acc;
  float mn = fminf(fminf(acc.x, acc.y), fminf(acc.z, acc.w));
  float mx = fmaxf(fmaxf(acc.x, acc.y), fmaxf(acc.z, acc.w));
  #pragma unroll
  for (int m = 1; m < 64; m <<= 1) {
    mn = fminf(mn, __shfl_xor(mn, m));
    mx = fmaxf(mx, __shfl_xor(mx, m));
  }
  __shared__ float wmn[4], wmx[4];
  if ((tid & 63) == 0) { wmn[tid >> 6] = mn; wmx[tid >> 6] = mx; }
  __syncthreads();
  if (tid == 0) {
    mn = fminf(fminf(wmn[0], wmn[1]), fminf(wmn[2], wmn[3]));
    mx = fmaxf(fmaxf(wmx[0], wmx[1]), fmaxf(wmx[2], wmx[3]));
    pmm[blk * 2 + 0] = mn; pmm[blk * 2 + 1] = mx;
  }
}

// ---- K3 (fused): normalize -> conv13 -> exact top-8192 select -> scatter sparse ----
__global__ __launch_bounds__(1024) void k_selfuse(const float* __restrict__ y,
                                                  const float* __restrict__ pmm,
                                                  const float* __restrict__ w,
                                                  float* __restrict__ sp) {
  int b = blockIdx.x;
  int tid = threadIdx.x;
  int wave = tid >> 6, lane = tid & 63;
  extern __shared__ float vsh[];            // 16896 floats, idx(j) = j + (j>>5)
  __shared__ float wl[ATT_K];
  __shared__ int redw[16][3];
  __shared__ int ctot[3];
  __shared__ int wtot[16];
  if (tid < ATT_K) wl[tid] = w[tid];

  float mn = pmm[b * 32], mx = pmm[b * 32 + 1];
  #pragma unroll
  for (int t = 1; t < 16; ++t) {
    mn = fminf(mn, pmm[b * 32 + t * 2]);
    mx = fmaxf(mx, pmm[b * 32 + t * 2 + 1]);
  }
  float inv = 1.f / (mx - mn);

  const float* yb = y + b * LL;
  #pragma unroll
  for (int c = 0; c < 4; ++c) {
    int i = c * 4096 + tid * 4;
    float4 t4 = *(const float4*)(yb + i);
    int p0 = i + (i >> 5);
    vsh[p0 + 0] = (t4.x - mn) * inv;
    vsh[p0 + 1] = (t4.y - mn) * inv;
    vsh[p0 + 2] = (t4.z - mn) * inv;
    vsh[p0 + 3] = (t4.w - mn) * inv;
  }
  __syncthreads();

  int e = tid * 16;
  unsigned kk[16];
  {
    float v28[28];
    #pragma unroll
    for (int i = 0; i < 28; ++i) {
      int j = e - 6 + i;
      v28[i] = (j >= 0 && j < LL) ? vsh[j + (j >> 5)] : 0.f;
    }
    #pragma unroll
    for (int i = 0; i < 16; ++i) {
      float acc = 0.f;
      #pragma unroll
      for (int k = 0; k < ATT_K; ++k) acc += v28[i + k] * wl[k];
      kk[i] = fkey(acc);
    }
  }

  unsigned p = 0; int need = KLIM;
  for (int pass = 0; pass < 16; ++pass) {
    int sh = 30 - pass * 2;
    unsigned himask = (pass == 0) ? 0u : (0xFFFFFFFFu << (sh + 2));
    int c3 = 0, c2 = 0, c1 = 0;
    #pragma unroll
    for (int i = 0; i < 16; ++i) {
      unsigned k2 = kk[i];
      if ((k2 & himask) == p) {
        unsigned bk = (k2 >> sh) & 3u;
        c3 += (bk == 3); c2 += (bk == 2); c1 += (bk == 1);
      }
    }
    #pragma unroll
    for (int m = 1; m < 64; m <<= 1) {
      c3 += __shfl_xor(c3, m); c2 += __shfl_xor(c2, m); c1 += __shfl_xor(c1, m);
    }
    if (lane == 0) { redw[wave][0] = c3; redw[wave][1] = c2; redw[wave][2] = c1; }
    __syncthreads();
    if (wave == 0) {
      int a0 = 0, a1 = 0, a2 = 0;
      if (lane < 16) { a0 = redw[lane][0]; a1 = redw[lane][1]; a2 = redw[lane][2]; }
      #pragma unroll
      for (int m = 1; m < 16; m <<= 1) {
        a0 += __shfl_xor(a0, m); a1 += __shfl_xor(a1, m); a2 += __shfl_xor(a2, m);
      }
      if (lane == 0) { ctot[0] = a0; ctot[1] = a1; ctot[2] = a2; }
    }
    __syncthreads();
    int C3 = ctot[0], C2 = ctot[1], C1 = ctot[2];
    if (C3 >= need)                { p |= 3u << sh; }
    else if (C3 + C2 >= need)      { p |= 2u << sh; need -= C3; }
    else if (C3 + C2 + C1 >= need) { p |= 1u << sh; need -= C3 + C2; }
    else                           { need -= C3 + C2 + C1; }
  }

  int cnt = 0;
  #pragma unroll
  for (int i = 0; i < 16; ++i) cnt += (kk[i] == p);
  int pre = cnt;
  #pragma unroll
  for (int m = 1; m < 64; m <<= 1) {
    int t = __shfl_up(pre, m);
    if (lane >= m) pre += t;
  }
  if (lane == 63) wtot[wave] = pre;
  __syncthreads();
  int base = 0;
  for (int t = 0; t < 16; ++t) if (t < wave) base += wtot[t];
  int rank = base + pre - cnt;

  float v28[28];
  #pragma unroll
  for (int i = 0; i < 28; ++i) {
    int j = e - 6 + i;
    v28[i] = (j >= 0 && j < LL) ? vsh[j + (j >> 5)] : 0.f;
  }
  float outv[16];
  #pragma unroll
  for (int i = 0; i < 16; ++i) {
    float acc = 0.f;
    #pragma unroll
    for (int k = 0; k < ATT_K; ++k) acc += v28[i + k] * wl[k];
    bool sel;
    if (kk[i] > p) sel = true;
    else if (kk[i] == p) { sel = (rank < need); rank++; }
    else sel = false;
    outv[i] = sel ? v28[i + 6] * (sigmoidf(acc) + 1.f) : 0.f;
  }
  float* spb = sp + b * LL + e;
  #pragma unroll
  for (int q = 0; q < 4; ++q)
    *(f32x4*)(spb + q * 4) = *(f32x4*)(outv + q * 4);
}

// ---- K4: split-K GEMM1 partials (R8 body, unchanged) ----
__global__ __launch_bounds__(1024, 4) void k_gemm1(const float* __restrict__ W1,
                                                   const float* __restrict__ sp,
                                                   float* __restrict__ p1) {
  __shared__ float sps[8][2048];            // 64 KB
  int bid = blockIdx.x;
  int s = bid & 7, g = bid >> 3;            // split, row-group
  int tid = threadIdx.x, wave = tid >> 6, lane = tid & 63;
  #pragma unroll
  for (int i = 0; i < 4; ++i) {
    int idx = i * 1024 + tid;               // f32x4 index 0..4095
    int bb = idx >> 9, off = (idx & 511) * 4;
    *(f32x4*)&sps[bb][off] = *(const f32x4*)(sp + (size_t)bb * LL + s * 2048 + off);
  }
  __syncthreads();
  int r0 = g * 94;
  int nr = N1 - r0; if (nr > 94) nr = 94;   // always even (94 or 78)
  int npair = nr >> 1;
  for (int p = wave; p < npair; p += 16) {
    int rA = r0 + p * 2;
    const float* wpA = W1 + (size_t)rA * LL + s * 2048;
    const float* wpB = wpA + LL;
    float acc0[8], acc1[8];
    #pragma unroll
    for (int bb = 0; bb < 8; ++bb) { acc0[bb] = 0.f; acc1[bb] = 0.f; }
    #pragma unroll 2
    for (int it = 0; it < 8; ++it) {
      int k0 = it * 256 + lane * 4;
      f32x4 wA = __builtin_nontemporal_load((const f32x4*)(wpA + k0));
      f32x4 wB = __builtin_nontemporal_load((const f32x4*)(wpB + k0));
      #pragma unroll
      for (int bb = 0; bb < 8; ++bb) {
        f32x4 s4 = *(const f32x4*)&sps[bb][k0];
        acc0[bb] += wA.x * s4.x + wA.y * s4.y + wA.z * s4.z + wA.w * s4.w;
        acc1[bb] += wB.x * s4.x + wB.y * s4.y + wB.z * s4.z + wB.w * s4.w;
      }
    }
    #pragma unroll
    for (int bb = 0; bb < 8; ++bb) {
      float a0 = acc0[bb], a1 = acc1[bb];
      #pragma unroll
      for (int m = 1; m < 64; m <<= 1) {
        a0 += __shfl_xor(a0, m);
        a1 += __shfl_xor(a1, m);
      }
      if (lane == 0) {
        p1[(size_t)(s * 8 + bb) * N1 + rA]     = a0;
        p1[(size_t)(s * 8 + bb) * N1 + rA + 1] = a1;
      }
    }
  }
}

// ---- K5: split-K GEMM2 partials (EXACT R8 body; geometry only: 30-row groups,
// grid = 3 splits x 164 groups = 492 blocks -> 2 resident blocks on ~all CUs) ----
__global__ __launch_bounds__(1024, 4) void k_gemm2(const float* __restrict__ W2,
                                                   const float* __restrict__ p1,
                                                   const float* __restrict__ b1,
                                                   float* __restrict__ p2) {
  __shared__ float hs[8][2048];             // 64 KB
  int bid = blockIdx.x;
  int s = bid / 164, g = bid % 164;
  int ks = s * 2048;
  int klen = (s == 2) ? (N1 - 4096) : 2048; // 1904 for last split
  int tid = threadIdx.x, wave = tid >> 6, lane = tid & 63;
  #pragma unroll
  for (int i = 0; i < 4; ++i) {
    int idx = i * 1024 + tid;               // 0..4095
    int bb = idx >> 9, off = (idx & 511) * 4;
    f32x4 v = {0.f, 0.f, 0.f, 0.f};
    if (off < klen) {
      int j = ks + off;
      #pragma unroll
      for (int q = 0; q < 8; ++q)
        v += *(const f32x4*)(p1 + (size_t)(q * 8 + bb) * N1 + j);
      v += *(const f32x4*)(b1 + j);
    }
    *(f32x4*)&hs[bb][off] = v;
  }
  __syncthreads();
  int r0 = g * 30;
  int nr = N2 - r0; if (nr > 30) nr = 30; if (nr < 0) nr = 0;  // even (30/24)
  int npair = nr >> 1;
  for (int p = wave; p < npair; p += 16) {
    int rA = r0 + p * 2;
    const float* wpA = W2 + (size_t)rA * N1 + ks;
    const float* wpB = wpA + N1;
    float acc0[8], acc1[8];
    #pragma unroll
    for (int bb = 0; bb < 8; ++bb) { acc0[bb] = 0.f; acc1[bb] = 0.f; }
    #pragma unroll 2
    for (int it = 0; it < 8; ++it) {
      int k0 = it * 256 + lane * 4;
      // hs is zero beyond klen, so products vanish; W read stays in-page.
      f32x4 wA = __builtin_nontemporal_load((const f32x4*)(wpA + k0));
      f32x4 wB = __builtin_nontemporal_load((const f32x4*)(wpB + k0));
      #pragma unroll
      for (int bb = 0; bb < 8; ++bb) {
        f32x4 s4 = *(const f32x4*)&hs[bb][k0];
        acc0[bb] += wA.x * s4.x + wA.y * s4.y + wA.z * s4.z + wA.w * s4.w;
        acc1[bb] += wB.x * s4.x + wB.y * s4.y + wB.z * s4.z + wB.w * s4.w;
      }
    }
    #pragma unroll
    for (int bb = 0; bb < 8; ++bb) {
      float a0 = acc0[bb], a1 = acc1[bb];
      #pragma unroll
      for (int m = 1; m < 64; m <<= 1) {
        a0 += __shfl_xor(a0, m);
        a1 += __shfl_xor(a1, m);
      }
      if (lane == 0) {
        p2[(size_t)(s * 8 + bb) * N2 + rA]     = a0;
        p2[(size_t)(s * 8 + bb) * N2 + rA + 1] = a1;
      }
    }
  }
}

// ---- K6: t[b,m] = sum_n h2[b,n]*Wc1[m,n], h2 reconstructed from 3 partials + b2 ----
__global__ void k_cls1(const float* __restrict__ p2, const float* __restrict__ b2,
                       const float* __restrict__ Wc1, float* __restrict__ t) {
  int bid = blockIdx.x; int b = bid >> 5, m = bid & 31;
  int tid = threadIdx.x;
  const float* wm = Wc1 + m * N2;
  float s = 0.f;
  for (int j = tid; j < N2; j += 256) {
    float hv = p2[(size_t)(0 * 8 + b) * N2 + j]
             + p2[(size_t)(1 * 8 + b) * N2 + j]
             + p2[(size_t)(2 * 8 + b) * N2 + j] + b2[j];
    s += hv * wm[j];
  }
  #pragma unroll
  for (int mm = 1; mm < 64; mm <<= 1) s += __shfl_xor(s, mm);
  __shared__ float red[4];
  if ((tid & 63) == 0) red[tid >> 6] = s;
  __syncthreads();
  if (tid == 0) t[b * 32 + m] = red[0] + red[1] + red[2] + red[3];
}

// ---- K7: logits = t @ Wc2^T ; log_softmax ----
__global__ void k_final(const float* __restrict__ t, const float* __restrict__ Wc2,
                        float* __restrict__ out) {
  int b = threadIdx.x;
  if (b < NB) {
    float lg[NCLS];
    #pragma unroll
    for (int k = 0; k < NCLS; ++k) {
      float s = 0.f;
      #pragma unroll
      for (int m = 0; m < 32; ++m) s += t[b * 32 + m] * Wc2[k * 32 + m];
      lg[k] = s;
    }
    float mx = lg[0];
    #pragma unroll
    for (int k = 1; k < NCLS; ++k) mx = fmaxf(mx, lg[k]);
    float se = 0.f;
    #pragma unroll
    for (int k = 0; k < NCLS; ++k) se += expf(lg[k] - mx);
    float lse = logf(se);
    #pragma unroll
    for (int k = 0; k < NCLS; ++k) out[b * NCLS + k] = lg[k] - mx - lse;
  }
}

extern "C" void kernel_launch(void* const* d_in, const int* in_sizes, int n_in,
                              void* d_out, int out_size, void* d_ws, size_t ws_size,
                              hipStream_t stream) {
  const float* adj   = (const float*)d_in[0];
  const float* eca_w = (const float*)d_in[1];
  const float* att_w = (const float*)d_in[2];
  const float* W1    = (const float*)d_in[3];
  const float* b1    = (const float*)d_in[4];
  const float* W2    = (const float*)d_in[5];
  const float* b2    = (const float*)d_in[6];
  const float* Wc1   = (const float*)d_in[7];
  const float* Wc2   = (const float*)d_in[8];
  float* out = (float*)d_out;
  float* ws  = (float*)d_ws;

  float* pooled = ws;              // 240
  float* pmm    = ws + 512;        // 256
  float* tbuf   = ws + 768;        // 256
  float* y      = ws + 1024;       // 131072
  float* sp     = y  + NB * LL;    // 131072
  float* p1     = sp + NB * LL;    // 8*8*6000 = 384000
  float* p2     = p1 + 384000;     // 3*8*4914 = 117936

  k_pool   <<<NB * NCH, 256, 0, stream>>>(adj, pooled);
  k_wsum   <<<NB * 16, 256, 0, stream>>>(adj, pooled, eca_w, y, pmm, out + NB * NCLS);
  k_selfuse<<<NB, 1024, 16896 * sizeof(float), stream>>>(y, pmm, att_w, sp);
  k_gemm1  <<<8 * 64, 1024, 0, stream>>>(W1, sp, p1);
  k_gemm2  <<<3 * 164, 1024, 0, stream>>>(W2, p1, b1, p2);
  k_cls1   <<<NB * 32, 256, 0, stream>>>(p2, b2, Wc1, tbuf);
  k_final  <<<1, 64, 0, stream>>>(tbuf, Wc2, out);
}